// Round 1
// baseline (569.680 us; speedup 1.0000x reference)
//
#include <hip/hip_runtime.h>
#include <hip/hip_bf16.h>

// B=16, N=1024, R=10, De=64, Dr=32, H=64, cat_in=960
// out[b,m,h] = relu( bias[h] + sum_r sum_n adj[b,r,m,n] * Yt[b,r,h,n] )
// Yt[b,r,h,n] = sum_d x[b,n,d]*W[h, r*96+d] + c[b,r,h]
// c[b,r,h]   = sum_d rel[b,r,d]*W[h, r*96+64+d]

typedef __bf16 bf16x8 __attribute__((ext_vector_type(8)));
typedef float  f32x4  __attribute__((ext_vector_type(4)));
typedef float  f32x8  __attribute__((ext_vector_type(8)));

// ---------------- c kernel: c[b,r,h] ----------------
__global__ void rgcn_c(const float* __restrict__ rel, const float* __restrict__ W,
                       float* __restrict__ cbuf) {
    const int h = threadIdx.x;            // 64
    const int b = blockIdx.x / 10;
    const int r = blockIdx.x % 10;
    const float* rp = rel + (size_t)(b * 10 + r) * 32;
    const float* wp = W + (size_t)h * 960 + r * 96 + 64;
    float acc = 0.f;
#pragma unroll
    for (int d = 0; d < 32; ++d) acc += rp[d] * wp[d];
    cbuf[(size_t)(b * 10 + r) * 64 + h] = acc;
}

// ---------------- prep kernel: Yt[b,r,h,n] (bf16) ----------------
__global__ __launch_bounds__(256)
void rgcn_prep(const float* __restrict__ x, const float* __restrict__ W,
               const float* __restrict__ cbuf, __bf16* __restrict__ yt) {
    const int n = blockIdx.x * 256 + threadIdx.x;   // 0..1023
    const int r = blockIdx.y;
    const int b = blockIdx.z;

    // load this thread's x row into registers (64 f32)
    float xr[64];
    const float* xp = x + ((size_t)b * 1024 + n) * 64;
#pragma unroll
    for (int j = 0; j < 16; ++j) {
        const float4 v = *(const float4*)(xp + j * 4);
        xr[j * 4 + 0] = v.x; xr[j * 4 + 1] = v.y;
        xr[j * 4 + 2] = v.z; xr[j * 4 + 3] = v.w;
    }

    const int br = b * 10 + r;
    const float* wbase = W + r * 96;                 // W[h*960 + r*96 + d]
    const float* cb = cbuf + (size_t)br * 64;
    __bf16* yb = yt + (size_t)br * 64 * 1024 + n;

    for (int h = 0; h < 64; ++h) {                   // h, d are wave-uniform -> W via SGPR loads
        float acc = cb[h];
        const float* wr = wbase + (size_t)h * 960;
#pragma unroll
        for (int d = 0; d < 64; ++d) acc += xr[d] * wr[d];
        yb[(size_t)h * 1024] = (__bf16)acc;
    }
}

// ---------------- main MFMA kernel ----------------
// grid: (8 mtiles, NRG r-groups, 16 b), 256 threads = 4 waves, wave owns 32m x 64h.
// A-frag: adj row (lane&15), k = (lane>>4)*8 + j   (contiguous, same map as B -> k-perm cancels)
// B-frag: Yt col  (lane&15), k = (lane>>4)*8 + j
// C/D  : col = lane&15, row = (lane>>4)*4 + reg    (m89-verified)
template<int NR, bool FUSE>
__global__ __launch_bounds__(256, 2)
void rgcn_main(const float* __restrict__ adj, const __bf16* __restrict__ yt,
               float* __restrict__ partial, const float* __restrict__ bias,
               float* __restrict__ dst) {
    const int mtile = blockIdx.x, rg = blockIdx.y, b = blockIdx.z;
    const int w = threadIdx.x >> 6, lane = threadIdx.x & 63;
    const int g = lane >> 4, lm = lane & 15;
    const int mbase = mtile * 128 + w * 32;

    f32x4 acc[2][4] = {};

    for (int rr = 0; rr < NR; ++rr) {
        const int br = b * 10 + rg * NR + rr;
        const float*  a0 = adj + (((size_t)br * 1024 + mbase + lm) << 10) + g * 8;
        const __bf16* y0 = yt  + (((size_t)br * 64 + lm) << 10) + g * 8;
        for (int n0 = 0; n0 < 1024; n0 += 32) {
            const f32x8 v0 = *(const f32x8*)(a0 + n0);
            const f32x8 v1 = *(const f32x8*)(a0 + (16 << 10) + n0);
            bf16x8 av0, av1;
#pragma unroll
            for (int j = 0; j < 8; ++j) {
                av0[j] = (__bf16)v0[j];
                av1[j] = (__bf16)v1[j];
            }
#pragma unroll
            for (int hf = 0; hf < 4; ++hf) {
                const bf16x8 bv = *(const bf16x8*)(y0 + (size_t)hf * 16 * 1024 + n0);
                acc[0][hf] = __builtin_amdgcn_mfma_f32_16x16x32_bf16(av0, bv, acc[0][hf], 0, 0, 0);
                acc[1][hf] = __builtin_amdgcn_mfma_f32_16x16x32_bf16(av1, bv, acc[1][hf], 0, 0, 0);
            }
        }
    }

    if (FUSE) {
        float bvals[4];
#pragma unroll
        for (int hf = 0; hf < 4; ++hf) bvals[hf] = bias[hf * 16 + lm];
        float* db = dst + ((size_t)b * 1024 + mbase) * 64;
#pragma unroll
        for (int mf = 0; mf < 2; ++mf)
#pragma unroll
            for (int hf = 0; hf < 4; ++hf)
#pragma unroll
                for (int reg = 0; reg < 4; ++reg) {
                    const int m = mf * 16 + g * 4 + reg;
                    const int h = hf * 16 + lm;
                    db[(size_t)m * 64 + h] = fmaxf(acc[mf][hf][reg] + bvals[hf], 0.f);
                }
    } else {
        float* pb = partial + (((size_t)rg * 16 + b) * 1024 + mbase) * 64;
#pragma unroll
        for (int mf = 0; mf < 2; ++mf)
#pragma unroll
            for (int hf = 0; hf < 4; ++hf)
#pragma unroll
                for (int reg = 0; reg < 4; ++reg) {
                    const int m = mf * 16 + g * 4 + reg;
                    const int h = hf * 16 + lm;
                    pb[(size_t)m * 64 + h] = acc[mf][hf][reg];
                }
    }
}

// ---------------- epilogue: sum 5 partials + bias + relu ----------------
__global__ __launch_bounds__(256)
void rgcn_epi(const float* __restrict__ partial, const float* __restrict__ bias,
              float* __restrict__ dst) {
    const size_t i = (size_t)blockIdx.x * 256 + threadIdx.x;  // f32x4 index, 262144 total
    const size_t off = i * 4;
    f32x4 s = {};
#pragma unroll
    for (int p = 0; p < 5; ++p)
        s += *(const f32x4*)(partial + (size_t)p * 1048576 + off);
    const f32x4 bv = *(const f32x4*)(bias + (int)(off & 63));
#pragma unroll
    for (int j = 0; j < 4; ++j) s[j] = fmaxf(s[j] + bv[j], 0.f);
    *(f32x4*)(dst + off) = s;
}

extern "C" void kernel_launch(void* const* d_in, const int* in_sizes, int n_in,
                              void* d_out, int out_size, void* d_ws, size_t ws_size,
                              hipStream_t stream) {
    const float* x   = (const float*)d_in[0];   // [16,1024,64]
    const float* rel = (const float*)d_in[1];   // [16,10,32]
    const float* adj = (const float*)d_in[2];   // [16,10,1024,1024]
    const float* W0  = (const float*)d_in[3];   // [64,960]
    const float* b0  = (const float*)d_in[4];   // [64]
    const float* W1  = (const float*)d_in[5];
    const float* b1  = (const float*)d_in[6];
    float* out = (float*)d_out;                 // [16,1024,64]

    char* ws = (char*)d_ws;
    __bf16* Yt   = (__bf16*)ws;                  // 20,971,520 B
    float* cbuf  = (float*)(ws + 20971520);      //     40,960 B
    float* x2    = (float*)(ws + 21012480);      //  4,194,304 B
    float* part  = (float*)(ws + 25206784);      // 20,971,520 B  (5 slices)
    const bool big = ws_size >= 46178304;

    for (int layer = 0; layer < 2; ++layer) {
        const float* xin  = layer ? x2 : x;
        const float* W    = layer ? W1 : W0;
        const float* bias = layer ? b1 : b0;
        float* dst        = layer ? out : x2;

        rgcn_c<<<160, 64, 0, stream>>>(rel, W, cbuf);
        rgcn_prep<<<dim3(4, 10, 16), 256, 0, stream>>>(xin, W, cbuf, Yt);
        if (big) {
            rgcn_main<2, false><<<dim3(8, 5, 16), 256, 0, stream>>>(adj, Yt, part, nullptr, nullptr);
            rgcn_epi<<<1024, 256, 0, stream>>>(part, bias, dst);
        } else {
            rgcn_main<10, true><<<dim3(8, 1, 16), 256, 0, stream>>>(adj, Yt, nullptr, bias, dst);
        }
    }
}